// Round 1
// baseline (90.453 us; speedup 1.0000x reference)
//
#include <hip/hip_runtime.h>
#include <math.h>

#define BLK 256
#define SUB 512   // cloud points staged in LDS per pass (12 KB total)

// Kernel 1: for each (b, s), partial min squared distance to preds and gts
// over the block's assigned N-chunk. Writes partial mins to ws.
__global__ __launch_bounds__(BLK) void sdf_partial_min(
    const float* __restrict__ grid,   // [B,S,3]
    const float* __restrict__ gts,    // [B,N,3]
    const float* __restrict__ preds,  // [B,N,3]
    float* __restrict__ ws,           // [2][B][S][nchunk]
    int B, int S, int N, int nchunk, int csize)
{
    __shared__ float lp[SUB * 3];
    __shared__ float lg[SUB * 3];

    const int tid   = threadIdx.x;
    const int stile = blockIdx.x;
    const int chunk = blockIdx.y;
    const int b     = blockIdx.z;

    const int n0 = chunk * csize;
    int n1 = n0 + csize;
    if (n1 > N) n1 = N;

    const int s = stile * BLK + tid;
    const float* xp = grid + ((size_t)b * S + s) * 3;
    const float x0 = xp[0], x1 = xp[1], x2 = xp[2];

    const float* pbase = preds + (size_t)b * N * 3;
    const float* gbase = gts   + (size_t)b * N * 3;

    float mp = 3.4e38f, mg = 3.4e38f;

    for (int nn = n0; nn < n1; nn += SUB) {
        int cnt = n1 - nn;
        if (cnt > SUB) cnt = SUB;
        const int nf = cnt * 3;

        __syncthreads();
        const float* pp = pbase + (size_t)nn * 3;
        const float* gg = gbase + (size_t)nn * 3;
        for (int i = tid; i < nf; i += BLK) {
            lp[i] = pp[i];
            lg[i] = gg[i];
        }
        __syncthreads();

        #pragma unroll 4
        for (int j = 0; j < cnt; ++j) {
            float dx = x0 - lp[3 * j + 0];
            float dy = x1 - lp[3 * j + 1];
            float dz = x2 - lp[3 * j + 2];
            float d2 = dx * dx + dy * dy + dz * dz;
            mp = fminf(mp, d2);
            dx = x0 - lg[3 * j + 0];
            dy = x1 - lg[3 * j + 1];
            dz = x2 - lg[3 * j + 2];
            d2 = dx * dx + dy * dy + dz * dz;
            mg = fminf(mg, d2);
        }
    }

    const size_t base = ((size_t)b * S + s) * nchunk + chunk;
    ws[base] = mp;
    ws[(size_t)B * S * nchunk + base] = mg;
}

// Kernel 2: reduce chunks -> min -> sqrt -> |diff| -> mean over S per batch.
__global__ __launch_bounds__(BLK) void sdf_reduce(
    const float* __restrict__ ws, float* __restrict__ out,
    int B, int S, int nchunk)
{
    const int b   = blockIdx.x;
    const int tid = threadIdx.x;
    const size_t cloud_off = (size_t)B * S * nchunk;

    float acc = 0.f;
    for (int s = tid; s < S; s += BLK) {
        const float* wp = ws + ((size_t)b * S + s) * nchunk;
        float mp = 3.4e38f, mg = 3.4e38f;
        for (int c = 0; c < nchunk; ++c) {
            mp = fminf(mp, wp[c]);
            mg = fminf(mg, wp[cloud_off + c]);
        }
        acc += fabsf(sqrtf(mp) - sqrtf(mg));
    }

    // wave (64-lane) shuffle reduction
    #pragma unroll
    for (int off = 32; off > 0; off >>= 1)
        acc += __shfl_down(acc, off, 64);

    __shared__ float wsum[BLK / 64];
    if ((tid & 63) == 0) wsum[tid >> 6] = acc;
    __syncthreads();
    if (tid == 0) {
        float t = 0.f;
        #pragma unroll
        for (int w = 0; w < BLK / 64; ++w) t += wsum[w];
        out[b] = t / (float)S;
    }
}

extern "C" void kernel_launch(void* const* d_in, const int* in_sizes, int n_in,
                              void* d_out, int out_size, void* d_ws, size_t ws_size,
                              hipStream_t stream) {
    const float* grid  = (const float*)d_in[0];
    const float* gts   = (const float*)d_in[1];
    const float* preds = (const float*)d_in[2];
    float* out = (float*)d_out;
    float* ws  = (float*)d_ws;

    const int B = 4, S = 4096, N = 4096;

    // Pick nchunk (power of 2 dividing N) that fits in workspace:
    // ws needs 2*B*S*nchunk floats.
    const size_t per_chunk_bytes = (size_t)2 * B * S * sizeof(float); // 128 KB
    int nchunk = 16;
    while (nchunk > 1 && (size_t)nchunk * per_chunk_bytes > ws_size) nchunk >>= 1;
    const int csize = N / nchunk;

    dim3 g1(S / BLK, nchunk, B);
    sdf_partial_min<<<g1, BLK, 0, stream>>>(grid, gts, preds, ws,
                                            B, S, N, nchunk, csize);
    sdf_reduce<<<B, BLK, 0, stream>>>(ws, out, B, S, nchunk);
}

// Round 2
// 34.467 us; speedup vs baseline: 2.6243x; 2.6243x over previous
//
#include <hip/hip_runtime.h>
#include <math.h>

#define BLK 256
#define INF 3.4e38f

// Kernel 1: each thread owns one grid point (b,s); scans its N-chunk of both
// clouds reading cloud points via block-uniform addresses (-> scalar loads),
// tracking min SQUARED distance (sqrt deferred). Partials written coalesced
// in [cloud][chunk][b][s] layout.
__global__ __launch_bounds__(BLK) void sdf_partial_min(
    const float* __restrict__ grid,   // [B,S,3]
    const float* __restrict__ gts,    // [B,N,3]
    const float* __restrict__ preds,  // [B,N,3]
    float* __restrict__ partial,      // [2][nchunk][B][S]
    int B, int S, int N, int nchunk, int csize)
{
    const int tid   = threadIdx.x;
    const int stile = blockIdx.x;
    const int chunk = blockIdx.y;
    const int b     = blockIdx.z;

    const int n0 = chunk * csize;
    const int s  = stile * BLK + tid;

    const float* xp = grid + ((size_t)b * S + s) * 3;
    const float x0 = xp[0], x1 = xp[1], x2 = xp[2];

    // Block-uniform cloud bases -> uniform (scalar) loads in the loop.
    const float* pp = preds + ((size_t)b * N + n0) * 3;
    const float* gg = gts   + ((size_t)b * N + n0) * 3;

    float mp0 = INF, mp1 = INF, mg0 = INF, mg1 = INF;

    #pragma unroll 2
    for (int j = 0; j < csize; j += 2) {
        // cloud point j -> accumulator 0
        {
            const float pa = pp[3 * j + 0], pb_ = pp[3 * j + 1], pc = pp[3 * j + 2];
            float dx = x0 - pa, dy = x1 - pb_, dz = x2 - pc;
            mp0 = fminf(mp0, dx * dx + dy * dy + dz * dz);
            const float ga = gg[3 * j + 0], gb = gg[3 * j + 1], gc = gg[3 * j + 2];
            dx = x0 - ga; dy = x1 - gb; dz = x2 - gc;
            mg0 = fminf(mg0, dx * dx + dy * dy + dz * dz);
        }
        // cloud point j+1 -> accumulator 1 (independent chain)
        {
            const float pa = pp[3 * j + 3], pb_ = pp[3 * j + 4], pc = pp[3 * j + 5];
            float dx = x0 - pa, dy = x1 - pb_, dz = x2 - pc;
            mp1 = fminf(mp1, dx * dx + dy * dy + dz * dz);
            const float ga = gg[3 * j + 3], gb = gg[3 * j + 4], gc = gg[3 * j + 5];
            dx = x0 - ga; dy = x1 - gb; dz = x2 - gc;
            mg1 = fminf(mg1, dx * dx + dy * dy + dz * dz);
        }
    }

    const float mp = fminf(mp0, mp1);
    const float mg = fminf(mg0, mg1);

    // layout [cloud][chunk][b][s]: coalesced write (consecutive tid = consecutive s)
    const size_t stride_bs = (size_t)B * S;
    partial[((size_t)chunk) * stride_bs + (size_t)b * S + s] = mp;
    partial[((size_t)(nchunk + chunk)) * stride_bs + (size_t)b * S + s] = mg;
}

// Kernel 2: per (tile, b): min over chunks (coalesced), sqrt, |diff|,
// block-sum -> one partial sum per (b, tile).
__global__ __launch_bounds__(BLK) void sdf_reduce(
    const float* __restrict__ partial, float* __restrict__ pb,
    int B, int S, int nchunk)
{
    const int tile = blockIdx.x;
    const int b    = blockIdx.y;
    const int tid  = threadIdx.x;
    const int s    = tile * BLK + tid;

    const size_t stride_bs = (size_t)B * S;
    const size_t base = (size_t)b * S + s;

    float mp = INF, mg = INF;
    for (int c = 0; c < nchunk; ++c) {
        mp = fminf(mp, partial[(size_t)c * stride_bs + base]);
        mg = fminf(mg, partial[(size_t)(nchunk + c) * stride_bs + base]);
    }

    float v = fabsf(sqrtf(mp) - sqrtf(mg));

    #pragma unroll
    for (int off = 32; off > 0; off >>= 1)
        v += __shfl_down(v, off, 64);

    __shared__ float wsum[BLK / 64];
    if ((tid & 63) == 0) wsum[tid >> 6] = v;
    __syncthreads();
    if (tid == 0) {
        float t = 0.f;
        #pragma unroll
        for (int w = 0; w < BLK / 64; ++w) t += wsum[w];
        pb[b * gridDim.x + tile] = t;
    }
}

// Kernel 3: final tiny reduction; ntile partial sums per batch -> out[b].
__global__ __launch_bounds__(64) void sdf_final(
    const float* __restrict__ pb, float* __restrict__ out,
    int B, int S, int ntile)
{
    const int tid = threadIdx.x;   // 0..63 ; b = tid/ntile when ntile==16
    float v = (tid < B * ntile) ? pb[tid] : 0.f;
    #pragma unroll
    for (int off = 8; off > 0; off >>= 1)
        v += __shfl_down(v, off, 16);
    if (tid < B * ntile && (tid & 15) == 0)
        out[tid / 16] = v / (float)S;
}

extern "C" void kernel_launch(void* const* d_in, const int* in_sizes, int n_in,
                              void* d_out, int out_size, void* d_ws, size_t ws_size,
                              hipStream_t stream) {
    const float* grid  = (const float*)d_in[0];
    const float* gts   = (const float*)d_in[1];
    const float* preds = (const float*)d_in[2];
    float* out = (float*)d_out;
    float* ws  = (float*)d_ws;

    const int B = 4, S = 4096, N = 4096;

    // partial mins need 2*nchunk*B*S floats (+ 64 floats for pb)
    const size_t per_chunk_bytes = (size_t)2 * B * S * sizeof(float); // 128 KB
    int nchunk = 16;
    while (nchunk > 1 &&
           (size_t)nchunk * per_chunk_bytes + 256 > ws_size) nchunk >>= 1;
    const int csize = N / nchunk;

    float* partial = ws;
    float* pb = ws + (size_t)2 * nchunk * B * S;

    const int ntile = S / BLK;                 // 16
    dim3 g1(ntile, nchunk, B);
    sdf_partial_min<<<g1, BLK, 0, stream>>>(grid, gts, preds, partial,
                                            B, S, N, nchunk, csize);
    dim3 g2(ntile, B);
    sdf_reduce<<<g2, BLK, 0, stream>>>(partial, pb, B, S, nchunk);
    sdf_final<<<1, 64, 0, stream>>>(pb, out, B, S, ntile);
}